// Round 3
// baseline (230.835 us; speedup 1.0000x reference)
//
#include <hip/hip_runtime.h>
#include <hip/hip_bf16.h>
#include <cstdint>
#include <cstddef>

// Problem constants
constexpr int T = 8;
constexpr int C = 256;     // feature channels = GEMM K
constexpr int N = 4096;    // H*W pixels per frame
constexpr float TEMP_INV = 14.285714285714286f;  // 1/0.07
constexpr float EPS = 1e-8f;

typedef __bf16 bf16;
typedef __bf16 bf16x8 __attribute__((ext_vector_type(8)));
typedef float floatx4 __attribute__((ext_vector_type(4)));

// ---------------------------------------------------------------------------
// async global->LDS, 16B per lane, wave-uniform LDS base + lane*16
__device__ __forceinline__ void async_copy16(const bf16* g, bf16* l) {
    __builtin_amdgcn_global_load_lds((const __attribute__((address_space(1))) void*)g,
                                     (__attribute__((address_space(3))) void*)l,
                                     16, 0, 0);
}

// ---------------------------------------------------------------------------
// Per-frame dice deviation -> use_curr flag; also zero the compaction counters.
__global__ void stats_kernel(const float* __restrict__ cur,
                             const float* __restrict__ hist,
                             float* __restrict__ flag,
                             int* __restrict__ nfg, int* __restrict__ nbg) {
    int t = blockIdx.x;
    int tid = threadIdx.x;
    float s1 = 0.f, sc = 0.f, sh = 0.f;
    for (int k = tid; k < N; k += 256) {
        float c = cur[t * N + k] > 0.5f ? 1.f : 0.f;
        float h = hist[t * N + k] > 0.5f ? 1.f : 0.f;
        s1 += c * h; sc += c; sh += h;
    }
    for (int o = 32; o > 0; o >>= 1) {
        s1 += __shfl_down(s1, o);
        sc += __shfl_down(sc, o);
        sh += __shfl_down(sh, o);
    }
    __shared__ float r1[4], r2[4], r3[4];
    int w = tid >> 6;
    if ((tid & 63) == 0) { r1[w] = s1; r2[w] = sc; r3[w] = sh; }
    __syncthreads();
    if (tid == 0) {
        float e1 = r1[0] + r1[1] + r1[2] + r1[3];
        float scs = r2[0] + r2[1] + r2[2] + r2[3];
        float shs = r3[0] + r3[1] + r3[2] + r3[3];
        float e2 = scs + shs;
        float m1 = (2.f * e1 + EPS) / (e2 + EPS);
        float m2 = (e1 + EPS) / (e2 - e1 + EPS);
        float dev = 1.f - 0.5f * (m1 + m2);
        flag[t] = (dev <= 0.0f) ? 1.f : 0.f;
        nfg[t] = 0;
        nbg[t] = 0;
    }
}

// ---------------------------------------------------------------------------
// labels -> d_out[0..T*N), zero negbuf, build per-frame compacted fg/bg lists.
// Grid: 64 blocks x 256 threads; block b -> frame b>>3, 512-pixel segment.
__global__ void labels_kernel(const float* __restrict__ cur,
                              const float* __restrict__ hist,
                              const float* __restrict__ flag,
                              float* __restrict__ out_labels,
                              float* __restrict__ negbuf,
                              unsigned short* __restrict__ fgidx,
                              unsigned short* __restrict__ bgidx,
                              int* __restrict__ nfg, int* __restrict__ nbg) {
    int t = blockIdx.x >> 3;
    int seg = (blockIdx.x & 7) * 512;
    int tid = threadIdx.x;
    int lane = tid & 63;
    bool use_curr = flag[t] != 0.f;
    for (int it = 0; it < 2; ++it) {
        int p = seg + it * 256 + tid;
        int gi = t * N + p;
        float lab = use_curr ? cur[gi] : hist[gi];
        out_labels[gi] = lab;
        negbuf[gi] = 0.f;
        bool fg = lab > 0.5f;
        unsigned long long b = __ballot(fg);
        unsigned long long lowmask = (lane == 63) ? 0x7fffffffffffffffull
                                                  : ((1ull << lane) - 1ull);
        int rank_fg = __popcll(b & lowmask);
        int rank_bg = __popcll((~b) & lowmask);
        int cnt_fg = __popcll(b);
        int base_fg = 0, base_bg = 0;
        if (lane == 0) {
            base_fg = atomicAdd(&nfg[t], cnt_fg);
            base_bg = atomicAdd(&nbg[t], 64 - cnt_fg);
        }
        base_fg = __shfl(base_fg, 0);
        base_bg = __shfl(base_bg, 0);
        if (fg) fgidx[t * N + base_fg + rank_fg] = (unsigned short)p;
        else    bgidx[t * N + base_bg + rank_bg] = (unsigned short)p;
    }
}

// ---------------------------------------------------------------------------
// Normalize features, transpose [T][C][N] -> bf16 [T][N][C], posdot = ||fhat||^2.
// bf16 LDS tile (34 KB -> 4 blocks/CU); sumsq fused into the load loop.
__global__ __launch_bounds__(256) void normalize_kernel(const float* __restrict__ feat,
                                                        bf16* __restrict__ fhat,
                                                        float* __restrict__ posdot) {
    __shared__ bf16 tile[64 * 258];    // [n][c], pad 258 (bf16) -> 1-bank row shift
    __shared__ float partial[256];
    __shared__ float rnorm_s[64];
    int t = blockIdx.x >> 6;           // 8 frames
    int n0 = (blockIdx.x & 63) * 64;   // 64 pixel rows per block
    int tid = threadIdx.x;
    int lane63 = tid & 63;             // pixel within tile
    int w = tid >> 6;                  // wave -> 64-channel slab
    const float* fb = feat + (size_t)t * C * N;
    float ss = 0.f;
    for (int it = 0; it < 64; ++it) {
        int c = w * 64 + it;
        float v = fb[(size_t)c * N + n0 + lane63];
        ss += v * v;
        tile[lane63 * 258 + c] = (bf16)v;
    }
    partial[tid] = ss;                 // partial[w*64 + n]
    __syncthreads();
    if (tid < 64) {
        float s = partial[tid] + partial[tid + 64] + partial[tid + 128] + partial[tid + 192];
        float r = 1.f / fmaxf(sqrtf(s), 1e-12f);
        rnorm_s[tid] = r;
        posdot[t * N + n0 + tid] = s * r * r;
    }
    __syncthreads();
    bf16* ob = fhat + ((size_t)t * N + n0) * C;
    for (int it = 0; it < 8; ++it) {
        int l = it * 256 + tid;        // short8 index, 0..2047
        int n = l >> 5;
        int c = (l & 31) * 8;
        float r = rnorm_s[n];
        bf16x8 vin = *(const bf16x8*)&tile[n * 258 + c];
        bf16x8 vo;
        for (int j = 0; j < 8; ++j) vo[j] = (bf16)((float)vin[j] * r);
        *(bf16x8*)(ob + l * 8) = vo;
    }
}

// ---------------------------------------------------------------------------
// Fused sim GEMM + exp + row reduction over compacted fg rows x bg cols.
// Persistent grid-stride blocks (512 = 2/CU), double-buffered LDS staging,
// one barrier per K-step; next tile's stage(0) overlaps current epilogue.
__global__ __launch_bounds__(256, 2) void sim_kernel(const bf16* __restrict__ fhat,
                                                     const unsigned short* __restrict__ fgidx,
                                                     const unsigned short* __restrict__ bgidx,
                                                     const int* __restrict__ nfg,
                                                     const int* __restrict__ nbg,
                                                     float* __restrict__ neg) {
    __shared__ bf16 a_lds[2][128 * 64];
    __shared__ bf16 b_lds[2][128 * 64];
    int tid = threadIdx.x;
    int lane = tid & 63;
    int w = tid >> 6;
    int ch = (lane & 7) ^ (lane >> 3);   // swizzled chunk this lane fetches
    int r0w = (w & 1) * 64;
    int c0w = (w >> 1) * 64;
    int quad = lane >> 4;

    for (int vt = blockIdx.x; vt < T * 32 * 32; vt += 512) {
        int t = vt >> 10;
        int rem = vt & 1023;
        int rowbase = (rem >> 5) * 128;
        int colbase = (rem & 31) * 128;
        int nfgt = nfg[t];
        int nbgt = nbg[t];
        if (rowbase >= nfgt || colbase >= nbgt) continue;   // block-uniform

        const bf16* fb = fhat + (size_t)t * N * C;
        const bf16* arp[4];
        const bf16* brp[4];
        for (int s = 0; s < 4; ++s) {
            int q = w * 4 + s;
            int row_l = q * 8 + (lane >> 3);          // 0..127 local row
            int ra = rowbase + row_l; if (ra >= nfgt) ra = nfgt - 1;
            int rb = colbase + row_l; if (rb >= nbgt) rb = nbgt - 1;
            arp[s] = fb + (size_t)fgidx[t * N + ra] * C + ch * 8;
            brp[s] = fb + (size_t)bgidx[t * N + rb] * C + ch * 8;
        }

        floatx4 acc[4][4];
        for (int i = 0; i < 4; ++i)
            for (int j = 0; j < 4; ++j)
                acc[i][j] = (floatx4){0.f, 0.f, 0.f, 0.f};

        // stage K-step 0 into buffer 0 (overlaps previous tile's epilogue;
        // buf0 readers all passed the previous tile's last barrier)
        for (int s = 0; s < 4; ++s) {
            int q = w * 4 + s;
            async_copy16(arp[s], &a_lds[0][q * 512]);
            async_copy16(brp[s], &b_lds[0][q * 512]);
        }

        for (int ks = 0; ks < 4; ++ks) {
            int buf = ks & 1;
            __syncthreads();             // drains stage(ks); protects buffers
            if (ks < 3) {                // prefetch next K-step into other buffer
                int k0 = (ks + 1) * 64;
                int nb2 = buf ^ 1;
                for (int s = 0; s < 4; ++s) {
                    int q = w * 4 + s;
                    async_copy16(arp[s] + k0, &a_lds[nb2][q * 512]);
                    async_copy16(brp[s] + k0, &b_lds[nb2][q * 512]);
                }
            }
            for (int kk = 0; kk < 64; kk += 32) {
                int chread = (kk >> 3) + quad;     // wanted chunk (0..7)
                bf16x8 af[4], bfr[4];
                for (int i = 0; i < 4; ++i) {
                    int r = r0w + 16 * i + (lane & 15);
                    int chs = chread ^ (r & 7);
                    af[i] = *(const bf16x8*)&a_lds[buf][r * 64 + chs * 8];
                }
                for (int j = 0; j < 4; ++j) {
                    int cidx = c0w + 16 * j + (lane & 15);
                    int chs = chread ^ (cidx & 7);
                    bfr[j] = *(const bf16x8*)&b_lds[buf][cidx * 64 + chs * 8];
                }
                for (int i = 0; i < 4; ++i)
                    for (int j = 0; j < 4; ++j)
                        acc[i][j] = __builtin_amdgcn_mfma_f32_16x16x32_bf16(af[i], bfr[j], acc[i][j], 0, 0, 0);
            }
        }

        // epilogue: exp + row-sum; mask padded cols, guard padded rows
        float bgv[4];
        for (int j = 0; j < 4; ++j) {
            int cidx = colbase + c0w + 16 * j + (lane & 15);
            bgv[j] = (cidx < nbgt) ? 1.f : 0.f;
        }
        for (int i = 0; i < 4; ++i) {
            for (int reg = 0; reg < 4; ++reg) {
                float msum = 0.f;
                for (int j = 0; j < 4; ++j)
                    msum += __expf(acc[i][j][reg] * TEMP_INV) * bgv[j];
                msum += __shfl_xor(msum, 1);
                msum += __shfl_xor(msum, 2);
                msum += __shfl_xor(msum, 4);
                msum += __shfl_xor(msum, 8);
                if ((lane & 15) == 0) {
                    int row = rowbase + r0w + 16 * i + quad * 4 + reg;  // compacted fg row
                    if (row < nfgt) atomicAdd(&neg[t * N + row], msum);
                }
            }
        }
    }
}

// ---------------------------------------------------------------------------
// Fused per-frame + final loss: 512 threads, wave t handles frame t.
__global__ void loss_kernel(const float* __restrict__ negbuf,
                            const float* __restrict__ posdot,
                            const unsigned short* __restrict__ fgidx,
                            const int* __restrict__ nfg,
                            const int* __restrict__ nbg,
                            float* __restrict__ out_loss) {
    int tid = threadIdx.x;
    int t = tid >> 6;
    int lane = tid & 63;
    int nfgt = nfg[t];
    float s = 0.f;
    for (int k = lane; k < nfgt; k += 64) {
        int pix = fgidx[t * N + k];
        float pos = __expf(posdot[t * N + pix] * TEMP_INV);
        float ng = negbuf[t * N + k];
        s += logf((pos + ng + EPS) / pos);
    }
    for (int o = 32; o > 0; o >>= 1) s += __shfl_down(s, o);
    __shared__ float fl[8], vv[8];
    if (lane == 0) {
        float valid = (nfgt > 0 && nbg[t] > 0) ? 1.f : 0.f;
        fl[t] = valid * (s / fmaxf((float)nfgt, 1.f));
        vv[t] = valid;
    }
    __syncthreads();
    if (tid == 0) {
        float ls = 0.f, v = 0.f;
        for (int i = 0; i < T; ++i) { ls += fl[i]; v += vv[i]; }
        out_loss[0] = (v > 0.f) ? ls / fmaxf(v, 1.f) : 0.f;
    }
}

// ---------------------------------------------------------------------------
extern "C" void kernel_launch(void* const* d_in, const int* in_sizes, int n_in,
                              void* d_out, int out_size, void* d_ws, size_t ws_size,
                              hipStream_t stream) {
    const float* cur  = (const float*)d_in[0];
    const float* hist = (const float*)d_in[1];
    const float* feat = (const float*)d_in[2];
    float* out = (float*)d_out;   // labels[32768] ++ loss[1]

    char* ws = (char*)d_ws;
    bf16*  fhat    = (bf16*)ws;                           // 16 MiB
    float* negbuf  = (float*)(ws + 16777216);             // 32768 f32 (compacted fg rows)
    float* posdot  = (float*)(ws + 16908288);             // 32768 f32
    unsigned short* fgidx = (unsigned short*)(ws + 17039360);  // 32768 u16
    unsigned short* bgidx = (unsigned short*)(ws + 17104896);  // 32768 u16
    float* flag    = (float*)(ws + 17170432);             // 8 f32
    int*   nfg     = (int*)(ws + 17170432 + 64);
    int*   nbg     = nfg + 8;

    stats_kernel<<<8, 256, 0, stream>>>(cur, hist, flag, nfg, nbg);
    labels_kernel<<<64, 256, 0, stream>>>(cur, hist, flag, out, negbuf, fgidx, bgidx, nfg, nbg);
    normalize_kernel<<<512, 256, 0, stream>>>(feat, fhat, posdot);
    sim_kernel<<<512, 256, 0, stream>>>(fhat, fgidx, bgidx, nfg, nbg, negbuf);
    loss_kernel<<<1, 512, 0, stream>>>(negbuf, posdot, fgidx, nfg, nbg, out + 32768);
}